// Round 2
// baseline (1151.387 us; speedup 1.0000x reference)
//
#include <hip/hip_runtime.h>
#include <stdint.h>

// Problem constants: C[8192,11008] = Xq*sx  @  ((W-off)*scl)^T, group=128
#define M_TOK 8192
#define K_IN  4096
#define N_OUT 11008

typedef float f32x4 __attribute__((ext_vector_type(4)));
typedef __bf16 bf16x8 __attribute__((ext_vector_type(8)));

typedef const uint32_t __attribute__((address_space(1)))* gas_ptr;
typedef uint32_t __attribute__((address_space(3)))* las_ptr;

__device__ __forceinline__ uint16_t f2bf(float f) {
  // round-to-nearest-even fp32 -> bf16 (inputs are finite normals)
  uint32_t u = __float_as_uint(f);
  return (uint16_t)((u + 0x7fffu + ((u >> 16) & 1u)) >> 16);
}

// ---- pass 1a: x_bf16[t,k] = bf16(qx[t,k] * sx[t]) ----
__global__ __launch_bounds__(256) void dequant_x_kernel(
    const float* __restrict__ qx, const float* __restrict__ sx,
    uint16_t* __restrict__ out) {
  int idx = blockIdx.x * 256 + threadIdx.x;   // float4 index; K=4096 -> 1024 f4/row
  int row = idx >> 10;
  float s = sx[row];
  float4 v = reinterpret_cast<const float4*>(qx)[idx];
  ushort4 o;
  o.x = f2bf(v.x * s);
  o.y = f2bf(v.y * s);
  o.z = f2bf(v.z * s);
  o.w = f2bf(v.w * s);
  reinterpret_cast<ushort4*>(out)[idx] = o;
}

// ---- pass 1b: w_bf16[o,k] = bf16((w[o,k] - off[o,k/128]) * scl[o,k/128]) ----
__global__ __launch_bounds__(256) void dequant_w_kernel(
    const float* __restrict__ w, const float* __restrict__ scl,
    const float* __restrict__ off, uint16_t* __restrict__ out) {
  int idx = blockIdx.x * 256 + threadIdx.x;   // float4 index
  int rg = idx >> 5;                          // (idx*4)/128 = row*32 + group
  float s = scl[rg];
  float o = off[rg];
  float4 v = reinterpret_cast<const float4*>(w)[idx];
  ushort4 u;
  u.x = f2bf((v.x - o) * s);
  u.y = f2bf((v.y - o) * s);
  u.z = f2bf((v.z - o) * s);
  u.w = f2bf((v.w - o) * s);
  reinterpret_cast<ushort4*>(out)[idx] = u;
}

// ---- pass 2: 256x256-tile, BK=64, 8-wave (4M x 2N), 8-phase pipelined GEMM ----
// C[M,N] = A[M,K] * B[N,K]^T, bf16 in / fp32 out.
// Wave decomposition 4M x 2N (each wave owns 64 rows x 128 cols): A fragments
// (8 ds_read_b128) are read ONCE per K-tile and carried across all 4 phases;
// B is read in 4 phase-local nq-groups of 4 b128 -> 24 b128/wave/K-tile
// (down from 32), putting MFMA (not LDS BW) on the critical path, with the
// same 48-VGPR peak fragment liveness as before (acc stays in AGPRs).
// Per phase: {ds_read ; global_load_lds stage(s) ; s_barrier ; lgkmcnt(0) ;
// setprio(1) 16xMFMA setprio(0) ; s_barrier}. Counted s_waitcnt vmcnt(7)
// once per K-tile (phase 4): 7 newest loads (= tile t+2's staged units) stay
// in flight across barriers; tile t+1 is guaranteed landed.
// Stage units are 64 LDS rows (1 global_load_lds per wave). Region freeing:
// A (all) + Bq0 free after ph1, Bq1 after ph2, Bq2 after ph3; Bq3 frees only
// after ph4 so tile t+1's Bq3 is staged during tile t's ph1.
// LDS: sA[2][256][64], sB[2][256][64] bf16 = 128 KiB, 16B-chunk XOR swizzle
// (chunk c of row r at slot c^(r&7)) applied via pre-swizzled global source.
// B rows permuted: LDS row L = nq*64 + xw  <->  global n-col
// (xw>>5)*128 + nq*32 + (xw&31), so each 64-row stage unit is one nq-group.
__global__ __launch_bounds__(512, 2) void gemm_bt_kernel(
    const uint16_t* __restrict__ A,   // [M,K] bf16 bits
    const uint16_t* __restrict__ B,   // [N,K] bf16 bits
    float* __restrict__ C) {          // [M,N] fp32
  constexpr int K = K_IN;
  constexpr int N = N_OUT;

  __shared__ __align__(128) uint16_t smem[65536];   // 128 KiB
  uint16_t* sA = smem;            // [2][256][64]
  uint16_t* sB = smem + 32768;    // [2][256][64] (row-permuted)

  const int tid  = threadIdx.x;
  const int lane = tid & 63;
  const int wave = tid >> 6;      // 0..7
  const int wm = wave >> 1;       // 0..3: M quadrant (64 rows)
  const int wn = wave & 1;        // 0..1: N half (128 cols)

  // XCD-aware bijective swizzle: nwg = 43*32 = 1376 = 8*172.
  // XCD chunk = 4 M-rows x 43 N-cols, m-fastest within 4-wide band.
  const int bid = blockIdx.x;
  const int xcd = bid & 7;
  const int wic = bid >> 3;                      // 0..171
  const int blockM = ((xcd << 2) | (wic & 3)) << 8;
  const int blockN = (wic >> 2) << 8;

  f32x4 acc[4][8];
#pragma unroll
  for (int i = 0; i < 4; ++i)
#pragma unroll
    for (int j = 0; j < 8; ++j) acc[i][j] = {0.f, 0.f, 0.f, 0.f};

  // Per-thread staging source bases. One global_load_lds per wave moves
  // 64 lanes x 16B = 8 LDS rows; lane l covers row (wave*8 + l>>3), chunk
  // slot l&7 which holds global chunk (l&7)^(l>>3)  [row&7 == l>>3].
  const int dr = lane >> 3;
  const int cg = (lane & 7) ^ dr;
  const int xw = wave * 8 + dr;                  // 0..63: row within a 64-row unit
  const uint16_t* aSrcBase = A + (size_t)(blockM + xw) * K + cg * 8;
  const uint16_t* bSrcBase =
      B + (size_t)(blockN + (xw >> 5) * 128 + (xw & 31)) * K + cg * 8;

  // Stage one 64-row unit (1 load/wave). A unit U covers tile rows U*64..+63.
#define STAGE_A1(TT, D, U)                                                      \
  __builtin_amdgcn_global_load_lds(                                             \
      (gas_ptr)(const void*)(aSrcBase + (size_t)((U) * 64) * K +                \
                             (size_t)(TT) * 64),                                \
      (las_ptr)(void*)(sA + (D) * 16384 + ((U) * 64 + wave * 8) * 64), 16, 0, 0)

  // B unit NQ covers n-cols {NQ*32..+31} and {128+NQ*32..+31} (row-permuted).
#define STAGE_B1(TT, D, NQ)                                                     \
  __builtin_amdgcn_global_load_lds(                                             \
      (gas_ptr)(const void*)(bSrcBase + (size_t)((NQ) * 32) * K +               \
                             (size_t)(TT) * 64),                                \
      (las_ptr)(void*)(sB + (D) * 16384 + ((NQ) * 64 + wave * 8) * 64), 16, 0, 0)

  bf16x8 af[4][2];   // A fragments: read once per K-tile, live all 4 phases
  bf16x8 bfr[2][2];  // B fragments: phase-local, recycled every phase

#define READ_A(D)                                                               \
  do {                                                                          \
    _Pragma("unroll") for (int mi_ = 0; mi_ < 4; ++mi_) {                       \
      const uint16_t* pa_ =                                                     \
          sA + (D) * 16384 + (wm * 64 + mi_ * 16 + (lane & 15)) * 64;           \
      _Pragma("unroll") for (int ks_ = 0; ks_ < 2; ++ks_) {                     \
        const int kc_ = ks_ * 4 + (lane >> 4);                                  \
        af[mi_][ks_] = *reinterpret_cast<const bf16x8*>(                        \
            pa_ + ((kc_ ^ (lane & 7)) << 3));                                   \
      }                                                                         \
    }                                                                           \
  } while (0)

#define READ_B(D, NQ)                                                           \
  do {                                                                          \
    _Pragma("unroll") for (int ni_ = 0; ni_ < 2; ++ni_) {                       \
      const uint16_t* pb_ =                                                     \
          sB + (D) * 16384 +                                                    \
          ((NQ) * 64 + wn * 32 + ni_ * 16 + (lane & 15)) * 64;                  \
      _Pragma("unroll") for (int ks_ = 0; ks_ < 2; ++ks_) {                     \
        const int kc_ = ks_ * 4 + (lane >> 4);                                  \
        bfr[ni_][ks_] = *reinterpret_cast<const bf16x8*>(                       \
            pb_ + ((kc_ ^ (lane & 7)) << 3));                                   \
      }                                                                         \
    }                                                                           \
  } while (0)

#define DO_MFMA(NQ)                                                             \
  do {                                                                          \
    __builtin_amdgcn_s_setprio(1);                                              \
    _Pragma("unroll") for (int ks_ = 0; ks_ < 2; ++ks_)                         \
    _Pragma("unroll") for (int mi_ = 0; mi_ < 4; ++mi_)                         \
    _Pragma("unroll") for (int ni_ = 0; ni_ < 2; ++ni_)                         \
        acc[mi_][(NQ) * 2 + ni_] =                                              \
            __builtin_amdgcn_mfma_f32_16x16x32_bf16(                            \
                af[mi_][ks_], bfr[ni_][ks_], acc[mi_][(NQ) * 2 + ni_], 0, 0, 0);\
    __builtin_amdgcn_s_setprio(0);                                              \
  } while (0)

#define BAR    __builtin_amdgcn_s_barrier()
#define LGKM0  asm volatile("s_waitcnt lgkmcnt(0)" ::: "memory")
#define VMCNT7 asm volatile("s_waitcnt vmcnt(7)" ::: "memory")

  // One K-tile: 4 phases, one B nq-group per phase. TN = t+1 (its dbuf = D1),
  // TNN = t+2 (its dbuf = D). Per wave per K-tile: 8 stage loads, 24 ds_reads.
#define TILE(D, D1, TN, TNN)                                                    \
  do {                                                                          \
    /* ph1: A + Bq0; stage Bq3 of tile t+1 (region freed by t-1's ph4) */       \
    READ_A(D);                                                                  \
    READ_B(D, 0);                                                               \
    STAGE_B1(TN, D1, 3);                                                        \
    BAR; LGKM0; DO_MFMA(0); BAR;                                                \
    /* ph2: Bq1; stage t+2 A0,A1,Bq0 (A + Bq0 freed after ph1) */               \
    READ_B(D, 1);                                                               \
    STAGE_A1(TNN, D, 0);                                                        \
    STAGE_A1(TNN, D, 1);                                                        \
    STAGE_B1(TNN, D, 0);                                                        \
    BAR; LGKM0; DO_MFMA(1); BAR;                                                \
    /* ph3: Bq2; stage t+2 A2,Bq1 (Bq1 freed after ph2) */                      \
    READ_B(D, 2);                                                               \
    STAGE_A1(TNN, D, 2);                                                        \
    STAGE_B1(TNN, D, 1);                                                        \
    BAR; LGKM0; DO_MFMA(2); BAR;                                                \
    /* ph4: Bq3; stage t+2 A3,Bq2; counted gate: t+1 landed, t+2 in flight */   \
    READ_B(D, 3);                                                               \
    STAGE_A1(TNN, D, 3);                                                        \
    STAGE_B1(TNN, D, 2);                                                        \
    VMCNT7;                                                                     \
    BAR; LGKM0; DO_MFMA(3); BAR;                                                \
  } while (0)

  // ---- prologue: tile0 complete (8 units) + tile1 minus Bq3 (7 units) ----
#pragma unroll
  for (int u = 0; u < 4; ++u) STAGE_A1(0, 0, u);
#pragma unroll
  for (int q = 0; q < 4; ++q) STAGE_B1(0, 0, q);
#pragma unroll
  for (int u = 0; u < 4; ++u) STAGE_A1(1, 1, u);
#pragma unroll
  for (int q = 0; q < 3; ++q) STAGE_B1(1, 1, q);
  VMCNT7;  // drains tile0's 8 loads; tile1's 7 may fly
  BAR;

  // ---- main loop: 32 iterations x 2 K-tiles (wrap at tail: dead-but-safe) --
  for (int i = 0; i < 32; ++i) {
    const int t1 = 2 * i + 1;
    const int t2 = (2 * i + 2) & 63;
    const int t3 = (2 * i + 3) & 63;
    TILE(0, 1, t1, t2);
    TILE(1, 0, t2, t3);
  }

  // ---- epilogue: C/D layout (16x16x32): col = lane&15, row = (lane>>4)*4+v
  const int crow0 = blockM + wm * 64 + (lane >> 4) * 4;
  const int ccol0 = blockN + wn * 128 + (lane & 15);
#pragma unroll
  for (int MI = 0; MI < 4; ++MI)
#pragma unroll
    for (int NI = 0; NI < 8; ++NI)
#pragma unroll
      for (int v = 0; v < 4; ++v)
        C[(size_t)(crow0 + MI * 16 + v) * N + (ccol0 + NI * 16)] =
            acc[MI][NI][v];

#undef STAGE_A1
#undef STAGE_B1
#undef READ_A
#undef READ_B
#undef DO_MFMA
#undef TILE
#undef BAR
#undef LGKM0
#undef VMCNT7
}

extern "C" void kernel_launch(void* const* d_in, const int* in_sizes, int n_in,
                              void* d_out, int out_size, void* d_ws, size_t ws_size,
                              hipStream_t stream) {
  const float* qx   = (const float*)d_in[0];  // [8192, 4096]
  const float* sx   = (const float*)d_in[1];  // [8192, 1]
  const float* w    = (const float*)d_in[2];  // [11008, 4096]
  const float* wscl = (const float*)d_in[3];  // [11008, 32]
  const float* woff = (const float*)d_in[4];  // [11008, 32]
  float* out = (float*)d_out;                 // [8192, 11008]

  // workspace: A_bf16 (64 MiB) then B_bf16 (86 MiB)
  uint16_t* Abf = (uint16_t*)d_ws;
  uint16_t* Bbf = Abf + (size_t)M_TOK * K_IN;

  {
    int n4 = M_TOK * K_IN / 4;                 // 8,388,608
    dequant_x_kernel<<<n4 / 256, 256, 0, stream>>>(qx, sx, Abf);
  }
  {
    int n4 = (int)((size_t)N_OUT * K_IN / 4);  // 11,272,192
    dequant_w_kernel<<<n4 / 256, 256, 0, stream>>>(w, wscl, woff, Bbf);
  }
  {
    dim3 grid(1376);                           // (11008/256) * (8192/256) = 43*32
    gemm_bt_kernel<<<grid, 512, 0, stream>>>(Abf, Bbf, out);
  }
}